// Round 3
// baseline (408.715 us; speedup 1.0000x reference)
//
#include <hip/hip_runtime.h>
#include <math.h>

#define DIM 512
#define SEQ 8192
#define BATCH 4
#define RTOT (BATCH*SEQ)   // 32768 rows
#define SCALE 0.125f       // 1/sqrt(64)

typedef unsigned short ushort_t;
typedef __attribute__((ext_vector_type(8))) short short8;
typedef __attribute__((ext_vector_type(4))) float float4v;

__device__ __forceinline__ float phi_f(float x){
    return x > 0.f ? x + 1.f : fmaxf(expf(x), 0.01f);
}

__device__ __forceinline__ unsigned short f2bf(float f){
    unsigned int u = __float_as_uint(f);
    u += 0x7fffu + ((u >> 16) & 1u);   // RNE
    return (unsigned short)(u >> 16);
}

// ws byte layout:
//   [0,4096) KV float[1024]; [4096,8192) Ks float[1024]
//   wqb ushort[512*512]; wob ushort[512*512]; wkvb ushort[4*128*512]
//   hb ushort[32768*512]; yb ushort[32768*512]
#define WS_NEED 68689920ull

// ---------- K0: rmsnorm factor + h = x*g*r cast to bf16 ----------
__global__ __launch_bounds__(256) void k_rmsh(const float* __restrict__ x, const float* __restrict__ g,
                                              float* __restrict__ wsf, ushort_t* __restrict__ hb){
    const int t = threadIdx.x, w = t>>6, L = t&63;
    const int row = blockIdx.x*4 + w;
    const float4* xr = (const float4*)(x + (size_t)row*DIM);
    float4 a = xr[L*2], c = xr[L*2+1];
    float s = a.x*a.x+a.y*a.y+a.z*a.z+a.w*a.w
            + c.x*c.x+c.y*c.y+c.z*c.z+c.w*c.w;
    #pragma unroll
    for(int off=1; off<64; off<<=1) s += __shfl_xor(s, off, 64);
    const float rf = rsqrtf(s*(1.0f/DIM) + 1e-6f);
    const float4* gr = (const float4*)g;
    float4 ga = gr[L*2], gb = gr[L*2+1];
    uint4 p;
    p.x = (unsigned)f2bf(a.x*ga.x*rf) | ((unsigned)f2bf(a.y*ga.y*rf)<<16);
    p.y = (unsigned)f2bf(a.z*ga.z*rf) | ((unsigned)f2bf(a.w*ga.w*rf)<<16);
    p.z = (unsigned)f2bf(c.x*gb.x*rf) | ((unsigned)f2bf(c.y*gb.y*rf)<<16);
    p.w = (unsigned)f2bf(c.z*gb.z*rf) | ((unsigned)f2bf(c.w*gb.w*rf)<<16);
    *(uint4*)(hb + (size_t)row*DIM + L*8) = p;
    if(blockIdx.x==0){
        for(int i=t;i<2048;i+=256) wsf[i]=0.f;
    }
}

// ---------- K0b: cast weights to bf16 ----------
__global__ __launch_bounds__(256) void k_wcast(const float* __restrict__ wq, const float* __restrict__ wk,
                                               const float* __restrict__ wv, const float* __restrict__ wo,
                                               ushort_t* __restrict__ wqb, ushort_t* __restrict__ wob,
                                               ushort_t* __restrict__ wkvb){
    const int idx = (blockIdx.x*256 + threadIdx.x)*4;
    const float* src; ushort_t* dst; int di;
    if(idx < 262144){ src = wq + idx; dst = wqb; di = idx; }
    else if(idx < 524288){ di = idx - 262144; src = wo + di; dst = wob; }
    else {
        int f = idx - 524288;
        int g = f >> 16, rem = f & 65535;
        int row = rem >> 9, col = rem & 511;
        src = (row < 64) ? (wk + (size_t)((g<<6)+row)*DIM + col)
                         : (wv + (size_t)((g<<6)+row-64)*DIM + col);
        dst = wkvb; di = f;
    }
    float4 v = *(const float4*)src;
    uint2 p;
    p.x = (unsigned)f2bf(v.x) | ((unsigned)f2bf(v.y)<<16);
    p.y = (unsigned)f2bf(v.z) | ((unsigned)f2bf(v.w)<<16);
    *(uint2*)(dst + di) = p;
}

// ---------- K1: k/v GEMM + phi + KV/K_sum reduction (reg-prefetch pipeline) ----------
__global__ __launch_bounds__(256,2) void k_kv_mfma(const ushort_t* __restrict__ hb,
                                                   const ushort_t* __restrict__ wkvb,
                                                   float* __restrict__ wsf){
    __shared__ ushort_t At[128*32];
    __shared__ ushort_t Bt[128*32];
    const int t = threadIdx.x, w = t>>6, L = t&63;
    const int lr = L&15, q = L>>4;
    const int r0 = blockIdx.x*128, gh = blockIdx.y;
    const int b = r0 >> 13;
    const int c0 = t, c1 = 256+t;
    const ushort_t* gA0 = hb + (size_t)(r0 + (c0>>2))*DIM + (c0&3)*8;
    const ushort_t* gA1 = hb + (size_t)(r0 + (c1>>2))*DIM + (c1&3)*8;
    const ushort_t* wb  = wkvb + (size_t)gh*128*DIM;
    const ushort_t* gB0 = wb + (size_t)(c0>>2)*DIM + (c0&3)*8;
    const ushort_t* gB1 = wb + (size_t)(c1>>2)*DIM + (c1&3)*8;

    float4v acc[2][8];
    #pragma unroll
    for(int i=0;i<2;i++)
        #pragma unroll
        for(int j=0;j<8;j++) acc[i][j] = (float4v){0.f,0.f,0.f,0.f};

    uint4 sa0[2], sa1[2], sb0[2], sb1[2];
    // prologue: T0 -> set1 -> LDS; T1 -> set0 (in flight)
    sa0[1]=*(const uint4*)gA0; sa1[1]=*(const uint4*)gA1;
    sb0[1]=*(const uint4*)gB0; sb1[1]=*(const uint4*)gB1;
    *(uint4*)(At+c0*8)=sa0[1]; *(uint4*)(At+c1*8)=sa1[1];
    *(uint4*)(Bt+c0*8)=sb0[1]; *(uint4*)(Bt+c1*8)=sb1[1];
    sa0[0]=*(const uint4*)(gA0+32); sa1[0]=*(const uint4*)(gA1+32);
    sb0[0]=*(const uint4*)(gB0+32); sb1[0]=*(const uint4*)(gB1+32);
    __syncthreads();

    #pragma unroll
    for(int ks=0; ks<16; ks++){
        const int pf = (ks+1)&1, wr_ = ks&1;
        if(ks<14){
            sa0[pf]=*(const uint4*)(gA0+(ks+2)*32); sa1[pf]=*(const uint4*)(gA1+(ks+2)*32);
            sb0[pf]=*(const uint4*)(gB0+(ks+2)*32); sb1[pf]=*(const uint4*)(gB1+(ks+2)*32);
        }
        short8 af[2], bf[8];
        #pragma unroll
        for(int mt=0; mt<2; mt++)
            af[mt] = *(const short8*)(At + (w*32 + mt*16 + lr)*32 + q*8);
        #pragma unroll
        for(int nt=0; nt<8; nt++)
            bf[nt] = *(const short8*)(Bt + (nt*16 + lr)*32 + q*8);
        #pragma unroll
        for(int mt=0; mt<2; mt++)
            #pragma unroll
            for(int nt=0; nt<8; nt++)
                acc[mt][nt] = __builtin_amdgcn_mfma_f32_16x16x32_bf16(af[mt], bf[nt], acc[mt][nt], 0,0,0);
        __syncthreads();
        if(ks<15){
            *(uint4*)(At+c0*8)=sa0[wr_]; *(uint4*)(At+c1*8)=sa1[wr_];
            *(uint4*)(Bt+c0*8)=sb0[wr_]; *(uint4*)(Bt+c1*8)=sb1[wr_];
            __syncthreads();
        }
    }

    #pragma unroll
    for(int nt=0; nt<4; nt++){
        float skv=0.f, sks=0.f;
        #pragma unroll
        for(int mt=0; mt<2; mt++)
            #pragma unroll
            for(int r=0; r<4; r++){
                float K = phi_f(acc[mt][nt][r]*SCALE);
                skv = fmaf(K, acc[mt][nt+4][r], skv);
                sks += K;
            }
        skv += __shfl_xor(skv,16,64); skv += __shfl_xor(skv,32,64);
        sks += __shfl_xor(sks,16,64); sks += __shfl_xor(sks,32,64);
        if(q==0){
            atomicAdd(&wsf[       b*256 + gh*64 + nt*16 + lr], skv);
            atomicAdd(&wsf[1024 + b*256 + gh*64 + nt*16 + lr], sks);
        }
    }
}

// ---------- K2: q GEMM + phi + Z + Y -> yb (reg-prefetch pipeline) ----------
__global__ __launch_bounds__(256,2) void k_q_mfma(const ushort_t* __restrict__ hb,
                                                  const ushort_t* __restrict__ wqb,
                                                  const float* __restrict__ wsf,
                                                  ushort_t* __restrict__ yb){
    __shared__ ushort_t smem[128*128];   // staging At=smem[0:4096), Bt=[4096:8192); epilogue Yt = whole
    ushort_t* At = smem;
    ushort_t* Bt = smem + 4096;
    const int t = threadIdx.x, w = t>>6, L = t&63;
    const int lr = L&15, q = L>>4;
    const int wr = w>>1, wc = w&1;
    const int r0 = blockIdx.x*128, ct = blockIdx.y;
    const int b = r0 >> 13;
    const int c0 = t, c1 = 256+t;
    const ushort_t* gA0 = hb + (size_t)(r0 + (c0>>2))*DIM + (c0&3)*8;
    const ushort_t* gA1 = hb + (size_t)(r0 + (c1>>2))*DIM + (c1&3)*8;
    const ushort_t* wbq = wqb + (size_t)ct*128*DIM;
    const ushort_t* gB0 = wbq + (size_t)(c0>>2)*DIM + (c0&3)*8;
    const ushort_t* gB1 = wbq + (size_t)(c1>>2)*DIM + (c1&3)*8;

    float4v acc[4][4];
    #pragma unroll
    for(int i=0;i<4;i++)
        #pragma unroll
        for(int j=0;j<4;j++) acc[i][j] = (float4v){0.f,0.f,0.f,0.f};

    uint4 sa0[2], sa1[2], sb0[2], sb1[2];
    sa0[1]=*(const uint4*)gA0; sa1[1]=*(const uint4*)gA1;
    sb0[1]=*(const uint4*)gB0; sb1[1]=*(const uint4*)gB1;
    *(uint4*)(At+c0*8)=sa0[1]; *(uint4*)(At+c1*8)=sa1[1];
    *(uint4*)(Bt+c0*8)=sb0[1]; *(uint4*)(Bt+c1*8)=sb1[1];
    sa0[0]=*(const uint4*)(gA0+32); sa1[0]=*(const uint4*)(gA1+32);
    sb0[0]=*(const uint4*)(gB0+32); sb1[0]=*(const uint4*)(gB1+32);
    __syncthreads();

    #pragma unroll
    for(int ks=0; ks<16; ks++){
        const int pf = (ks+1)&1, wr_ = ks&1;
        if(ks<14){
            sa0[pf]=*(const uint4*)(gA0+(ks+2)*32); sa1[pf]=*(const uint4*)(gA1+(ks+2)*32);
            sb0[pf]=*(const uint4*)(gB0+(ks+2)*32); sb1[pf]=*(const uint4*)(gB1+(ks+2)*32);
        }
        short8 af[4], bf[4];
        #pragma unroll
        for(int mt=0; mt<4; mt++)
            af[mt] = *(const short8*)(At + (wr*64 + mt*16 + lr)*32 + q*8);
        #pragma unroll
        for(int nt=0; nt<4; nt++)
            bf[nt] = *(const short8*)(Bt + (wc*64 + nt*16 + lr)*32 + q*8);
        #pragma unroll
        for(int mt=0; mt<4; mt++)
            #pragma unroll
            for(int nt=0; nt<4; nt++)
                acc[mt][nt] = __builtin_amdgcn_mfma_f32_16x16x32_bf16(af[mt], bf[nt], acc[mt][nt], 0,0,0);
        __syncthreads();
        if(ks<15){
            *(uint4*)(At+c0*8)=sa0[wr_]; *(uint4*)(At+c1*8)=sa1[wr_];
            *(uint4*)(Bt+c0*8)=sb0[wr_]; *(uint4*)(Bt+c1*8)=sb1[wr_];
            __syncthreads();
        }
    }

    // epilogue: Q=phi(acc*SCALE); Z; Y -> Yt (bf16) -> yb
    float ksf[4], kvf[4];
    #pragma unroll
    for(int nt=0; nt<4; nt++){
        ksf[nt] = wsf[1024 + b*256 + ct*64 + nt*16 + lr];
        kvf[nt] = wsf[       b*256 + ct*64 + nt*16 + lr];
    }
    #pragma unroll
    for(int mt=0; mt<4; mt++)
        #pragma unroll
        for(int nt=0; nt<4; nt++)
            #pragma unroll
            for(int r=0; r<4; r++)
                acc[mt][nt][r] = phi_f(acc[mt][nt][r]*SCALE);
    float zi[4][4];
    #pragma unroll
    for(int mt=0; mt<4; mt++)
        #pragma unroll
        for(int r=0; r<4; r++){
            float zv = acc[mt][0][r]*ksf[0] + acc[mt][1][r]*ksf[1]
                     + acc[mt][2][r]*ksf[2] + acc[mt][3][r]*ksf[3];
            zv += __shfl_xor(zv,1,64); zv += __shfl_xor(zv,2,64);
            zv += __shfl_xor(zv,4,64); zv += __shfl_xor(zv,8,64);
            zi[mt][r] = 1.0f/(zv + 1e-6f);
        }
    ushort_t* Yt = smem;   // reuse all 32 KB (staging dead after last barrier)
    #pragma unroll
    for(int mt=0; mt<4; mt++)
        #pragma unroll
        for(int nt=0; nt<4; nt++)
            #pragma unroll
            for(int r=0; r<4; r++)
                Yt[(wr*64 + mt*16 + q*4 + r)*128 + wc*64 + nt*16 + lr]
                    = f2bf(acc[mt][nt][r]*kvf[nt]*zi[mt][r]);
    __syncthreads();
    #pragma unroll
    for(int i=0;i<8;i++){
        int u = (i*256 + t)*8;
        int rr = u>>7, cc = u&127;
        *(uint4*)(yb + (size_t)(r0+rr)*DIM + ct*128 + cc) = *(const uint4*)(Yt + u);
    }
}

// ---------- K3: out = Y @ wo^T (reg-prefetch pipeline), fp32 store ----------
__global__ __launch_bounds__(256,2) void k_out_mfma(const ushort_t* __restrict__ yb,
                                                    const ushort_t* __restrict__ wob,
                                                    float* __restrict__ out){
    __shared__ ushort_t At[128*32];
    __shared__ ushort_t Bt[128*32];
    const int t = threadIdx.x, w = t>>6, L = t&63;
    const int lr = L&15, q = L>>4;
    const int wr = w>>1, wc = w&1;
    const int r0 = blockIdx.x*128, ct = blockIdx.y;
    const int c0 = t, c1 = 256+t;
    const ushort_t* gA0 = yb + (size_t)(r0 + (c0>>2))*DIM + (c0&3)*8;
    const ushort_t* gA1 = yb + (size_t)(r0 + (c1>>2))*DIM + (c1&3)*8;
    const ushort_t* wbo = wob + (size_t)ct*128*DIM;
    const ushort_t* gB0 = wbo + (size_t)(c0>>2)*DIM + (c0&3)*8;
    const ushort_t* gB1 = wbo + (size_t)(c1>>2)*DIM + (c1&3)*8;

    float4v acc[4][4];
    #pragma unroll
    for(int i=0;i<4;i++)
        #pragma unroll
        for(int j=0;j<4;j++) acc[i][j] = (float4v){0.f,0.f,0.f,0.f};

    uint4 sa0[2], sa1[2], sb0[2], sb1[2];
    sa0[1]=*(const uint4*)gA0; sa1[1]=*(const uint4*)gA1;
    sb0[1]=*(const uint4*)gB0; sb1[1]=*(const uint4*)gB1;
    *(uint4*)(At+c0*8)=sa0[1]; *(uint4*)(At+c1*8)=sa1[1];
    *(uint4*)(Bt+c0*8)=sb0[1]; *(uint4*)(Bt+c1*8)=sb1[1];
    sa0[0]=*(const uint4*)(gA0+32); sa1[0]=*(const uint4*)(gA1+32);
    sb0[0]=*(const uint4*)(gB0+32); sb1[0]=*(const uint4*)(gB1+32);
    __syncthreads();

    #pragma unroll
    for(int ks=0; ks<16; ks++){
        const int pf = (ks+1)&1, wr_ = ks&1;
        if(ks<14){
            sa0[pf]=*(const uint4*)(gA0+(ks+2)*32); sa1[pf]=*(const uint4*)(gA1+(ks+2)*32);
            sb0[pf]=*(const uint4*)(gB0+(ks+2)*32); sb1[pf]=*(const uint4*)(gB1+(ks+2)*32);
        }
        short8 af[4], bf[4];
        #pragma unroll
        for(int mt=0; mt<4; mt++)
            af[mt] = *(const short8*)(At + (wr*64 + mt*16 + lr)*32 + q*8);
        #pragma unroll
        for(int nt=0; nt<4; nt++)
            bf[nt] = *(const short8*)(Bt + (wc*64 + nt*16 + lr)*32 + q*8);
        #pragma unroll
        for(int mt=0; mt<4; mt++)
            #pragma unroll
            for(int nt=0; nt<4; nt++)
                acc[mt][nt] = __builtin_amdgcn_mfma_f32_16x16x32_bf16(af[mt], bf[nt], acc[mt][nt], 0,0,0);
        __syncthreads();
        if(ks<15){
            *(uint4*)(At+c0*8)=sa0[wr_]; *(uint4*)(At+c1*8)=sa1[wr_];
            *(uint4*)(Bt+c0*8)=sb0[wr_]; *(uint4*)(Bt+c1*8)=sb1[wr_];
            __syncthreads();
        }
    }
    #pragma unroll
    for(int mt=0; mt<4; mt++)
        #pragma unroll
        for(int nt=0; nt<4; nt++)
            #pragma unroll
            for(int r=0; r<4; r++)
                out[(size_t)(r0 + wr*64 + mt*16 + q*4 + r)*DIM + ct*128 + wc*64 + nt*16 + lr]
                    = acc[mt][nt][r];
}

// ================= FALLBACK (fp32 vector; only if ws too small) =================
#define OFF_KV 0
#define OFF_KS 1024
#define OFF_R  2048

__global__ __launch_bounds__(256) void k_rms_f32(const float* __restrict__ x, float* __restrict__ ws){
    const int row  = blockIdx.x*4 + (threadIdx.x>>6);
    const int lane = threadIdx.x & 63;
    const float4* xr = (const float4*)(x + (size_t)row*DIM);
    float4 a = xr[lane];
    float4 b = xr[lane+64];
    float s = a.x*a.x+a.y*a.y+a.z*a.z+a.w*a.w
            + b.x*b.x+b.y*b.y+b.z*b.z+b.w*b.w;
    #pragma unroll
    for(int off=32; off; off>>=1) s += __shfl_xor(s, off, 64);
    if(lane==0) ws[OFF_R+row] = rsqrtf(s*(1.0f/DIM) + 1e-6f);
    if(blockIdx.x==0){
        for(int i=threadIdx.x;i<2048;i+=256) ws[i]=0.f;
    }
}

__global__ __launch_bounds__(256) void k_kv_f32(const float* __restrict__ x, const float* __restrict__ g,
                                            const float* __restrict__ wk, const float* __restrict__ wv,
                                            float* __restrict__ ws){
    __shared__ float sAT[16][128];
    __shared__ float sB[16][128];
    __shared__ float rl[128];
    __shared__ float red[64][16];
    const int t  = threadIdx.x;
    const int r0 = blockIdx.x * 128;
    const int gh = blockIdx.y;
    const int b  = r0 / SEQ;
    if(t < 128) rl[t] = ws[OFF_R + r0 + t];
    const int ti = t & 15, tj = t >> 4;
    const int ri = ti*4, cj = tj*4;
    const int srow = t & 127;
    const int skk  = (t >> 7) * 8;
    const float* xrow = x + (size_t)(r0 + srow)*DIM + skk;
    const float* wrow = (srow < 64) ? (wk + (size_t)(gh*64 + srow)*DIM + skk)
                                    : (wv + (size_t)(gh*64 + (srow-64))*DIM + skk);
    const float* gp = g + skk;
    float accK[8][4], accV[8][4];
    #pragma unroll
    for(int i=0;i<8;i++)
        #pragma unroll
        for(int j=0;j<4;j++){ accK[i][j]=0.f; accV[i][j]=0.f; }
    __syncthreads();
    const float rr = rl[srow];
    for(int k0=0;k0<DIM;k0+=16){
        float4 xa = *(const float4*)(xrow + k0);
        float4 xb = *(const float4*)(xrow + k0 + 4);
        float4 ga = *(const float4*)(gp + k0);
        float4 gb = *(const float4*)(gp + k0 + 4);
        float4 wa = *(const float4*)(wrow + k0);
        float4 wb = *(const float4*)(wrow + k0 + 4);
        __syncthreads();
        sAT[skk+0][srow]=xa.x*ga.x*rr; sAT[skk+1][srow]=xa.y*ga.y*rr;
        sAT[skk+2][srow]=xa.z*ga.z*rr; sAT[skk+3][srow]=xa.w*ga.w*rr;
        sAT[skk+4][srow]=xb.x*gb.x*rr; sAT[skk+5][srow]=xb.y*gb.y*rr;
        sAT[skk+6][srow]=xb.z*gb.z*rr; sAT[skk+7][srow]=xb.w*gb.w*rr;
        sB[skk+0][srow]=wa.x; sB[skk+1][srow]=wa.y; sB[skk+2][srow]=wa.z; sB[skk+3][srow]=wa.w;
        sB[skk+4][srow]=wb.x; sB[skk+5][srow]=wb.y; sB[skk+6][srow]=wb.z; sB[skk+7][srow]=wb.w;
        __syncthreads();
        #pragma unroll
        for(int kk=0;kk<16;kk++){
            float4 a0 = *(const float4*)&sAT[kk][ri];
            float4 a1 = *(const float4*)&sAT[kk][ri+64];
            float4 bk = *(const float4*)&sB[kk][cj];
            float4 bv = *(const float4*)&sB[kk][cj+64];
            float av[8] = {a0.x,a0.y,a0.z,a0.w,a1.x,a1.y,a1.z,a1.w};
            float bk4[4]= {bk.x,bk.y,bk.z,bk.w};
            float bv4[4]= {bv.x,bv.y,bv.z,bv.w};
            #pragma unroll
            for(int i=0;i<8;i++)
                #pragma unroll
                for(int j=0;j<4;j++){
                    accK[i][j] = fmaf(av[i], bk4[j], accK[i][j]);
                    accV[i][j] = fmaf(av[i], bv4[j], accV[i][j]);
                }
        }
    }
    float pKV[4], pKs[4];
    #pragma unroll
    for(int j=0;j<4;j++){
        float skv=0.f, sks=0.f;
        #pragma unroll
        for(int i=0;i<8;i++){
            float kvv = phi_f(accK[i][j]*SCALE);
            skv = fmaf(kvv, accV[i][j], skv);
            sks += kvv;
        }
        pKV[j]=skv; pKs[j]=sks;
    }
    __syncthreads();
    #pragma unroll
    for(int j=0;j<4;j++) red[cj+j][ti] = pKV[j];
    __syncthreads();
    if(t<64){
        float s2=0.f;
        for(int i=0;i<16;i++) s2 += red[t][i];
        atomicAdd(&ws[OFF_KV + b*256 + gh*64 + t], s2);
    }
    __syncthreads();
    #pragma unroll
    for(int j=0;j<4;j++) red[cj+j][ti] = pKs[j];
    __syncthreads();
    if(t<64){
        float s2=0.f;
        for(int i=0;i<16;i++) s2 += red[t][i];
        atomicAdd(&ws[OFF_KS + b*256 + gh*64 + t], s2);
    }
}

__global__ __launch_bounds__(256) void k_qo_f32(const float* __restrict__ x, const float* __restrict__ g,
                                            const float* __restrict__ wq, const float* __restrict__ wo,
                                            const float* __restrict__ ws, float* __restrict__ out){
    __shared__ float qT[512][32];
    __shared__ float sAT[16][32];
    __shared__ float sB[16][128];
    __shared__ float rl[32];
    __shared__ float KVl[256];
    __shared__ float Ksl[256];
    __shared__ float zb[256];
    const int t  = threadIdx.x;
    const int r0 = blockIdx.x * 32;
    const int b  = r0 / SEQ;
    if(t<32) rl[t] = ws[OFF_R + r0 + t];
    KVl[t] = ws[OFF_KV + b*256 + t];
    Ksl[t] = ws[OFF_KS + b*256 + t];
    const int ti = t & 7, tj = t >> 3;
    const int ri = ti*4, cj = tj*4;
    const int srow = t & 31, skk = (t>>5)*2;
    const int sj = t & 127, skkB = (t>>7)*8;
    const float* xrow = x + (size_t)(r0+srow)*DIM + skk;
    const float* gp = g + skk;
    __syncthreads();
    const float rr = rl[srow];
    for(int ct=0; ct<4; ct++){
        const float* wqb = wq + (size_t)(ct*128 + sj)*DIM + skkB;
        float acc[4][4];
        #pragma unroll
        for(int i=0;i<4;i++)
            #pragma unroll
            for(int j=0;j<4;j++) acc[i][j]=0.f;
        for(int k0=0;k0<DIM;k0+=16){
            float2 xa = *(const float2*)(xrow + k0);
            float2 ga = *(const float2*)(gp + k0);
            float4 wa = *(const float4*)(wqb + k0);
            float4 wb2= *(const float4*)(wqb + k0 + 4);
            __syncthreads();
            sAT[skk+0][srow] = xa.x*ga.x*rr;
            sAT[skk+1][srow] = xa.y*ga.y*rr;
            sB[skkB+0][sj]=wa.x; sB[skkB+1][sj]=wa.y; sB[skkB+2][sj]=wa.z; sB[skkB+3][sj]=wa.w;
            sB[skkB+4][sj]=wb2.x; sB[skkB+5][sj]=wb2.y; sB[skkB+6][sj]=wb2.z; sB[skkB+7][sj]=wb2.w;
            __syncthreads();
            #pragma unroll
            for(int kk=0;kk<16;kk++){
                float4 a = *(const float4*)&sAT[kk][ri];
                float4 bb= *(const float4*)&sB[kk][cj];
                float av[4]={a.x,a.y,a.z,a.w};
                float bv[4]={bb.x,bb.y,bb.z,bb.w};
                #pragma unroll
                for(int i=0;i<4;i++)
                    #pragma unroll
                    for(int j=0;j<4;j++)
                        acc[i][j] = fmaf(av[i], bv[j], acc[i][j]);
            }
        }
        #pragma unroll
        for(int i=0;i<4;i++)
            #pragma unroll
            for(int j=0;j<4;j++)
                qT[ct*128+cj+j][ri+i] = phi_f(acc[i][j]*SCALE);
    }
    __syncthreads();
    {
        const int row = t>>3, h = t&7;
        const float* ks = &Ksl[(h>>1)*64];
        float z = 0.f;
        #pragma unroll
        for(int d=0;d<64;d++) z = fmaf(qT[h*64+d][row], ks[d], z);
        zb[row*8+h] = 1.0f/(z + 1e-6f);
    }
    __syncthreads();
    #pragma unroll 4
    for(int i2=0;i2<64;i2++){
        int f = i2*256 + t;
        int col = f>>5, row = f&31;
        int h = col>>6;
        float kvv = KVl[((h>>1)<<6) + (col&63)];
        qT[col][row] *= kvv * zb[row*8+h];
    }
    __syncthreads();
    for(int ct=0;ct<4;ct++){
        const float* wob = wo + (size_t)(ct*128 + sj)*DIM + skkB;
        float acc[4][4];
        #pragma unroll
        for(int i=0;i<4;i++)
            #pragma unroll
            for(int j=0;j<4;j++) acc[i][j]=0.f;
        for(int k0=0;k0<DIM;k0+=16){
            float4 wa = *(const float4*)(wob + k0);
            float4 wb2= *(const float4*)(wob + k0 + 4);
            __syncthreads();
            sB[skkB+0][sj]=wa.x; sB[skkB+1][sj]=wa.y; sB[skkB+2][sj]=wa.z; sB[skkB+3][sj]=wa.w;
            sB[skkB+4][sj]=wb2.x; sB[skkB+5][sj]=wb2.y; sB[skkB+6][sj]=wb2.z; sB[skkB+7][sj]=wb2.w;
            __syncthreads();
            #pragma unroll
            for(int kk=0;kk<16;kk++){
                float4 a = *(const float4*)&qT[k0+kk][ri];
                float4 bb= *(const float4*)&sB[kk][cj];
                float av[4]={a.x,a.y,a.z,a.w};
                float bv[4]={bb.x,bb.y,bb.z,bb.w};
                #pragma unroll
                for(int i=0;i<4;i++)
                    #pragma unroll
                    for(int j=0;j<4;j++)
                        acc[i][j] = fmaf(av[i], bv[j], acc[i][j]);
            }
        }
        #pragma unroll
        for(int i=0;i<4;i++){
            float4 st; st.x=acc[i][0]; st.y=acc[i][1]; st.z=acc[i][2]; st.w=acc[i][3];
            *(float4*)(out + (size_t)(r0+ri+i)*DIM + ct*128 + cj) = st;
        }
    }
}

extern "C" void kernel_launch(void* const* d_in, const int* in_sizes, int n_in,
                              void* d_out, int out_size, void* d_ws, size_t ws_size,
                              hipStream_t stream){
    (void)in_sizes; (void)n_in; (void)out_size;
    const float* x  = (const float*)d_in[0];
    const float* g  = (const float*)d_in[1];
    const float* wq = (const float*)d_in[2];
    const float* wk = (const float*)d_in[3];
    const float* wv = (const float*)d_in[4];
    const float* wo = (const float*)d_in[5];
    float* out = (float*)d_out;

    if(ws_size >= WS_NEED){
        float* wsf = (float*)d_ws;
        ushort_t* wqb  = (ushort_t*)((char*)d_ws + 8192);
        ushort_t* wob  = wqb  + 262144;
        ushort_t* wkvb = wob  + 262144;
        ushort_t* hb   = wkvb + 262144;
        ushort_t* yb   = hb   + 16777216;

        hipLaunchKernelGGL(k_rmsh,    dim3(RTOT/4),      dim3(256), 0, stream, x, g, wsf, hb);
        hipLaunchKernelGGL(k_wcast,   dim3(768),         dim3(256), 0, stream, wq, wk, wv, wo, wqb, wob, wkvb);
        hipLaunchKernelGGL(k_kv_mfma, dim3(RTOT/128, 4), dim3(256), 0, stream, hb, wkvb, wsf);
        hipLaunchKernelGGL(k_q_mfma,  dim3(RTOT/128, 4), dim3(256), 0, stream, hb, wqb, wsf, yb);
        hipLaunchKernelGGL(k_out_mfma,dim3(RTOT/128, 4), dim3(256), 0, stream, yb, wob, out);
    } else {
        float* ws = (float*)d_ws;
        hipLaunchKernelGGL(k_rms_f32, dim3(RTOT/4),      dim3(256), 0, stream, x, ws);
        hipLaunchKernelGGL(k_kv_f32,  dim3(RTOT/128, 4), dim3(256), 0, stream, x, g, wk, wv, ws);
        hipLaunchKernelGGL(k_qo_f32,  dim3(RTOT/32),     dim3(256), 0, stream, x, g, wq, wo, ws, out);
    }
}

// Round 5
// 240.843 us; speedup vs baseline: 1.6970x; 1.6970x over previous
//
#include <hip/hip_runtime.h>
#include <math.h>

#define DIM 512
#define SEQ 8192
#define BATCH 4
#define RTOT (BATCH*SEQ)   // 32768 rows
#define SCALE 0.125f       // 1/sqrt(64)

typedef unsigned short ushort_t;
typedef __attribute__((ext_vector_type(8))) short short8;
typedef __attribute__((ext_vector_type(4))) float float4v;

__device__ __forceinline__ float phi_f(float x){
    return x > 0.f ? x + 1.f : fmaxf(expf(x), 0.01f);
}

__device__ __forceinline__ unsigned short f2bf(float f){
    unsigned int u = __float_as_uint(f);
    u += 0x7fffu + ((u >> 16) & 1u);   // RNE
    return (unsigned short)(u >> 16);
}

// ws byte layout:
//   [0,4096) KV float[1024] (b*256 + kvhead*64 + d); [4096,8192) Ks float[1024]
//   wqb ushort[512*512]; wob ushort[512*512]; wkvb ushort[4*128*512]
//   hb ushort[32768*512]
#define WS_NEED 35135488ull

// ---------- K0: rmsnorm factor + h = x*g*r cast to bf16 ----------
__global__ __launch_bounds__(256) void k_rmsh(const float* __restrict__ x, const float* __restrict__ g,
                                              float* __restrict__ wsf, ushort_t* __restrict__ hb){
    const int t = threadIdx.x, w = t>>6, L = t&63;
    const int row = blockIdx.x*4 + w;
    const float4* xr = (const float4*)(x + (size_t)row*DIM);
    float4 a = xr[L*2], c = xr[L*2+1];
    float s = a.x*a.x+a.y*a.y+a.z*a.z+a.w*a.w
            + c.x*c.x+c.y*c.y+c.z*c.z+c.w*c.w;
    #pragma unroll
    for(int off=1; off<64; off<<=1) s += __shfl_xor(s, off, 64);
    const float rf = rsqrtf(s*(1.0f/DIM) + 1e-6f);
    const float4* gr = (const float4*)g;
    float4 ga = gr[L*2], gb = gr[L*2+1];
    uint4 p;
    p.x = (unsigned)f2bf(a.x*ga.x*rf) | ((unsigned)f2bf(a.y*ga.y*rf)<<16);
    p.y = (unsigned)f2bf(a.z*ga.z*rf) | ((unsigned)f2bf(a.w*ga.w*rf)<<16);
    p.z = (unsigned)f2bf(c.x*gb.x*rf) | ((unsigned)f2bf(c.y*gb.y*rf)<<16);
    p.w = (unsigned)f2bf(c.z*gb.z*rf) | ((unsigned)f2bf(c.w*gb.w*rf)<<16);
    *(uint4*)(hb + (size_t)row*DIM + L*8) = p;
    if(blockIdx.x==0){
        for(int i=t;i<2048;i+=256) wsf[i]=0.f;
    }
}

// ---------- K0b: cast weights to bf16 ----------
__global__ __launch_bounds__(256) void k_wcast(const float* __restrict__ wq, const float* __restrict__ wk,
                                               const float* __restrict__ wv, const float* __restrict__ wo,
                                               ushort_t* __restrict__ wqb, ushort_t* __restrict__ wob,
                                               ushort_t* __restrict__ wkvb){
    const int idx = (blockIdx.x*256 + threadIdx.x)*4;
    const float* src; ushort_t* dst; int di;
    if(idx < 262144){ src = wq + idx; dst = wqb; di = idx; }
    else if(idx < 524288){ di = idx - 262144; src = wo + di; dst = wob; }
    else {
        int f = idx - 524288;
        int g = f >> 16, rem = f & 65535;
        int row = rem >> 9, col = rem & 511;
        src = (row < 64) ? (wk + (size_t)((g<<6)+row)*DIM + col)
                         : (wv + (size_t)((g<<6)+row-64)*DIM + col);
        dst = wkvb; di = f;
    }
    float4 v = *(const float4*)src;
    uint2 p;
    p.x = (unsigned)f2bf(v.x) | ((unsigned)f2bf(v.y)<<16);
    p.y = (unsigned)f2bf(v.z) | ((unsigned)f2bf(v.w)<<16);
    *(uint2*)(dst + di) = p;
}

// A-slab staging into fragment layout: As[ks][row][32], ks=0..15, row=0..63
__device__ __forceinline__ void stage_A(const ushort_t* __restrict__ src, size_t r0,
                                        ushort_t* As, int w, int L){
    #pragma unroll
    for(int i=0;i<16;i++){
        const int row = i*4 + w;
        uint4 v = *(const uint4*)(src + (size_t)(r0+row)*DIM + L*8);
        *(uint4*)(&As[(L>>2)*2048 + row*32 + (L&3)*8]) = v;
    }
}

// ---------- K1: k/v GEMM, barrier-free main loop; wave w = kv head w ----------
__global__ __launch_bounds__(256,2) void k_kv2(const ushort_t* __restrict__ hb,
                                               const ushort_t* __restrict__ wkvb,
                                               float* __restrict__ wsf){
    __shared__ ushort_t As[32768];   // 64 KB
    const int t = threadIdx.x, w = t>>6, L = t&63;
    const int lr = L&15, q = L>>4;
    const size_t r0 = (size_t)blockIdx.x*64;
    const int b = (int)(r0 >> 13);

    stage_A(hb, r0, As, w, L);
    __syncthreads();

    const ushort_t* bp[8];
    #pragma unroll
    for(int nt=0;nt<8;nt++)
        bp[nt] = wkvb + ((size_t)w*128 + nt*16 + lr)*DIM + q*8;

    float4v acc[4][8];
    #pragma unroll
    for(int i=0;i<4;i++)
        #pragma unroll
        for(int j=0;j<8;j++) acc[i][j] = (float4v){0.f,0.f,0.f,0.f};

    #pragma unroll
    for(int ks=0; ks<16; ks++){
        short8 bf[8];
        #pragma unroll
        for(int nt=0;nt<8;nt++) bf[nt] = *(const short8*)(bp[nt] + ks*32);
        short8 af[4];
        #pragma unroll
        for(int mt=0;mt<4;mt++)
            af[mt] = *(const short8*)(As + ks*2048 + (mt*16+lr)*32 + q*8);
        #pragma unroll
        for(int mt=0;mt<4;mt++)
            #pragma unroll
            for(int nt=0;nt<8;nt++)
                acc[mt][nt] = __builtin_amdgcn_mfma_f32_16x16x32_bf16(af[mt], bf[nt], acc[mt][nt], 0,0,0);
    }

    // epilogue: K = phi(acck*SCALE); KV += K*V; Ks += K. kv head = w, d = nt*16+lr
    #pragma unroll
    for(int nt=0; nt<4; nt++){
        float skv=0.f, sks=0.f;
        #pragma unroll
        for(int mt=0; mt<4; mt++)
            #pragma unroll
            for(int r=0; r<4; r++){
                float K = phi_f(acc[mt][nt][r]*SCALE);
                skv = fmaf(K, acc[mt][nt+4][r], skv);
                sks += K;
            }
        skv += __shfl_xor(skv,16,64); skv += __shfl_xor(skv,32,64);
        sks += __shfl_xor(sks,16,64); sks += __shfl_xor(sks,32,64);
        if(q==0){
            atomicAdd(&wsf[       b*256 + w*64 + nt*16 + lr], skv);
            atomicAdd(&wsf[1024 + b*256 + w*64 + nt*16 + lr], sks);
        }
    }
}

// ---------- K2: fused q-GEMM -> phi/Z/Y (LDS) -> out-GEMM; wave w = cols w*128.. ----------
__global__ __launch_bounds__(256,2) void k_qout(const ushort_t* __restrict__ hb,
                                                const ushort_t* __restrict__ wqb,
                                                const ushort_t* __restrict__ wob,
                                                const float* __restrict__ wsf,
                                                float* __restrict__ out){
    __shared__ ushort_t As[32768];   // 64 KB: h-slab, then reused as Y-slab
    const int t = threadIdx.x, w = t>>6, L = t&63;
    const int lr = L&15, q = L>>4;
    const size_t r0 = (size_t)blockIdx.x*64;
    const int b = (int)(r0 >> 13);

    stage_A(hb, r0, As, w, L);
    __syncthreads();

    float4v acc[4][8];
    #pragma unroll
    for(int i=0;i<4;i++)
        #pragma unroll
        for(int j=0;j<8;j++) acc[i][j] = (float4v){0.f,0.f,0.f,0.f};

    {   // ---- phase 1: Q = h @ wq^T (cols w*128 .. w*128+127) ----
        const ushort_t* bp[8];
        #pragma unroll
        for(int nt=0;nt<8;nt++)
            bp[nt] = wqb + ((size_t)w*128 + nt*16 + lr)*DIM + q*8;
        #pragma unroll
        for(int ks=0; ks<16; ks++){
            short8 bf[8];
            #pragma unroll
            for(int nt=0;nt<8;nt++) bf[nt] = *(const short8*)(bp[nt] + ks*32);
            short8 af[4];
            #pragma unroll
            for(int mt=0;mt<4;mt++)
                af[mt] = *(const short8*)(As + ks*2048 + (mt*16+lr)*32 + q*8);
            #pragma unroll
            for(int mt=0;mt<4;mt++)
                #pragma unroll
                for(int nt=0;nt<8;nt++)
                    acc[mt][nt] = __builtin_amdgcn_mfma_f32_16x16x32_bf16(af[mt], bf[nt], acc[mt][nt], 0,0,0);
        }
    }

    // ---- phi + Z + Y ----
    // column col = w*128 + nt*16 + lr -> head h = 2w + (nt>>2); KV/Ks are per KV HEAD = h>>1 = w
    float ksf[8], kvf[8];
    #pragma unroll
    for(int nt=0;nt<8;nt++){
        const int d = (nt&3)*16 + lr;
        kvf[nt] = wsf[       b*256 + w*64 + d];
        ksf[nt] = wsf[1024 + b*256 + w*64 + d];
    }
    #pragma unroll
    for(int mt=0;mt<4;mt++)
        #pragma unroll
        for(int nt=0;nt<8;nt++)
            #pragma unroll
            for(int r=0;r<4;r++)
                acc[mt][nt][r] = phi_f(acc[mt][nt][r]*SCALE);
    float zi0[4][4], zi1[4][4];
    #pragma unroll
    for(int mt=0;mt<4;mt++)
        #pragma unroll
        for(int r=0;r<4;r++){
            float z0 = acc[mt][0][r]*ksf[0] + acc[mt][1][r]*ksf[1]
                     + acc[mt][2][r]*ksf[2] + acc[mt][3][r]*ksf[3];
            float z1 = acc[mt][4][r]*ksf[4] + acc[mt][5][r]*ksf[5]
                     + acc[mt][6][r]*ksf[6] + acc[mt][7][r]*ksf[7];
            z0 += __shfl_xor(z0,1,64); z0 += __shfl_xor(z0,2,64);
            z0 += __shfl_xor(z0,4,64); z0 += __shfl_xor(z0,8,64);
            z1 += __shfl_xor(z1,1,64); z1 += __shfl_xor(z1,2,64);
            z1 += __shfl_xor(z1,4,64); z1 += __shfl_xor(z1,8,64);
            zi0[mt][r] = 1.0f/(z0 + 1e-6f);
            zi1[mt][r] = 1.0f/(z1 + 1e-6f);
        }
    __syncthreads();   // all waves done reading h-slab from As
    // write Y (bf16) into As in fragment layout: (row, col) -> As[(col>>5)*2048 + row*32 + (col&31)]
    #pragma unroll
    for(int mt=0;mt<4;mt++)
        #pragma unroll
        for(int nt=0;nt<8;nt++)
            #pragma unroll
            for(int r=0;r<4;r++){
                float zi = (nt<4) ? zi0[mt][r] : zi1[mt][r];
                float y = acc[mt][nt][r]*kvf[nt]*zi;
                As[(w*4 + (nt>>1))*2048 + (mt*16 + q*4 + r)*32 + (nt&1)*16 + lr] = f2bf(y);
            }
    __syncthreads();

    // ---- phase 2: out = Y @ wo^T (cols w*128 .. w*128+127) ----
    #pragma unroll
    for(int i=0;i<4;i++)
        #pragma unroll
        for(int j=0;j<8;j++) acc[i][j] = (float4v){0.f,0.f,0.f,0.f};
    {
        const ushort_t* bp[8];
        #pragma unroll
        for(int nt=0;nt<8;nt++)
            bp[nt] = wob + ((size_t)w*128 + nt*16 + lr)*DIM + q*8;
        #pragma unroll
        for(int ks=0; ks<16; ks++){
            short8 bf[8];
            #pragma unroll
            for(int nt=0;nt<8;nt++) bf[nt] = *(const short8*)(bp[nt] + ks*32);
            short8 af[4];
            #pragma unroll
            for(int mt=0;mt<4;mt++)
                af[mt] = *(const short8*)(As + ks*2048 + (mt*16+lr)*32 + q*8);
            #pragma unroll
            for(int mt=0;mt<4;mt++)
                #pragma unroll
                for(int nt=0;nt<8;nt++)
                    acc[mt][nt] = __builtin_amdgcn_mfma_f32_16x16x32_bf16(af[mt], bf[nt], acc[mt][nt], 0,0,0);
        }
    }
    #pragma unroll
    for(int mt=0;mt<4;mt++)
        #pragma unroll
        for(int nt=0;nt<8;nt++)
            #pragma unroll
            for(int r=0;r<4;r++)
                out[(r0 + mt*16 + q*4 + r)*DIM + w*128 + nt*16 + lr] = acc[mt][nt][r];
}

// ================= FALLBACK (fp32 vector; only if ws too small) =================
#define OFF_KV 0
#define OFF_KS 1024
#define OFF_R  2048

__global__ __launch_bounds__(256) void k_rms_f32(const float* __restrict__ x, float* __restrict__ ws){
    const int row  = blockIdx.x*4 + (threadIdx.x>>6);
    const int lane = threadIdx.x & 63;
    const float4* xr = (const float4*)(x + (size_t)row*DIM);
    float4 a = xr[lane];
    float4 b = xr[lane+64];
    float s = a.x*a.x+a.y*a.y+a.z*a.z+a.w*a.w
            + b.x*b.x+b.y*b.y+b.z*b.z+b.w*b.w;
    #pragma unroll
    for(int off=32; off; off>>=1) s += __shfl_xor(s, off, 64);
    if(lane==0) ws[OFF_R+row] = rsqrtf(s*(1.0f/DIM) + 1e-6f);
    if(blockIdx.x==0){
        for(int i=threadIdx.x;i<2048;i+=256) ws[i]=0.f;
    }
}

__global__ __launch_bounds__(256) void k_kv_f32(const float* __restrict__ x, const float* __restrict__ g,
                                            const float* __restrict__ wk, const float* __restrict__ wv,
                                            float* __restrict__ ws){
    __shared__ float sAT[16][128];
    __shared__ float sB[16][128];
    __shared__ float rl[128];
    __shared__ float red[64][16];
    const int t  = threadIdx.x;
    const int r0 = blockIdx.x * 128;
    const int gh = blockIdx.y;
    const int b  = r0 / SEQ;
    if(t < 128) rl[t] = ws[OFF_R + r0 + t];
    const int ti = t & 15, tj = t >> 4;
    const int ri = ti*4, cj = tj*4;
    const int srow = t & 127;
    const int skk  = (t >> 7) * 8;
    const float* xrow = x + (size_t)(r0 + srow)*DIM + skk;
    const float* wrow = (srow < 64) ? (wk + (size_t)(gh*64 + srow)*DIM + skk)
                                    : (wv + (size_t)(gh*64 + (srow-64))*DIM + skk);
    const float* gp = g + skk;
    float accK[8][4], accV[8][4];
    #pragma unroll
    for(int i=0;i<8;i++)
        #pragma unroll
        for(int j=0;j<4;j++){ accK[i][j]=0.f; accV[i][j]=0.f; }
    __syncthreads();
    const float rr = rl[srow];
    for(int k0=0;k0<DIM;k0+=16){
        float4 xa = *(const float4*)(xrow + k0);
        float4 xb = *(const float4*)(xrow + k0 + 4);
        float4 ga = *(const float4*)(gp + k0);
        float4 gb = *(const float4*)(gp + k0 + 4);
        float4 wa = *(const float4*)(wrow + k0);
        float4 wb = *(const float4*)(wrow + k0 + 4);
        __syncthreads();
        sAT[skk+0][srow]=xa.x*ga.x*rr; sAT[skk+1][srow]=xa.y*ga.y*rr;
        sAT[skk+2][srow]=xa.z*ga.z*rr; sAT[skk+3][srow]=xa.w*ga.w*rr;
        sAT[skk+4][srow]=xb.x*gb.x*rr; sAT[skk+5][srow]=xb.y*gb.y*rr;
        sAT[skk+6][srow]=xb.z*gb.z*rr; sAT[skk+7][srow]=xb.w*gb.w*rr;
        sB[skk+0][srow]=wa.x; sB[skk+1][srow]=wa.y; sB[skk+2][srow]=wa.z; sB[skk+3][srow]=wa.w;
        sB[skk+4][srow]=wb.x; sB[skk+5][srow]=wb.y; sB[skk+6][srow]=wb.z; sB[skk+7][srow]=wb.w;
        __syncthreads();
        #pragma unroll
        for(int kk=0;kk<16;kk++){
            float4 a0 = *(const float4*)&sAT[kk][ri];
            float4 a1 = *(const float4*)&sAT[kk][ri+64];
            float4 bk = *(const float4*)&sB[kk][cj];
            float4 bv = *(const float4*)&sB[kk][cj+64];
            float av[8] = {a0.x,a0.y,a0.z,a0.w,a1.x,a1.y,a1.z,a1.w};
            float bk4[4]= {bk.x,bk.y,bk.z,bk.w};
            float bv4[4]= {bv.x,bv.y,bv.z,bv.w};
            #pragma unroll
            for(int i=0;i<8;i++)
                #pragma unroll
                for(int j=0;j<4;j++){
                    accK[i][j] = fmaf(av[i], bk4[j], accK[i][j]);
                    accV[i][j] = fmaf(av[i], bv4[j], accV[i][j]);
                }
        }
    }
    float pKV[4], pKs[4];
    #pragma unroll
    for(int j=0;j<4;j++){
        float skv=0.f, sks=0.f;
        #pragma unroll
        for(int i=0;i<8;i++){
            float kvv = phi_f(accK[i][j]*SCALE);
            skv = fmaf(kvv, accV[i][j], skv);
            sks += kvv;
        }
        pKV[j]=skv; pKs[j]=sks;
    }
    __syncthreads();
    #pragma unroll
    for(int j=0;j<4;j++) red[cj+j][ti] = pKV[j];
    __syncthreads();
    if(t<64){
        float s2=0.f;
        for(int i=0;i<16;i++) s2 += red[t][i];
        atomicAdd(&ws[OFF_KV + b*256 + gh*64 + t], s2);
    }
    __syncthreads();
    #pragma unroll
    for(int j=0;j<4;j++) red[cj+j][ti] = pKs[j];
    __syncthreads();
    if(t<64){
        float s2=0.f;
        for(int i=0;i<16;i++) s2 += red[t][i];
        atomicAdd(&ws[OFF_KS + b*256 + gh*64 + t], s2);
    }
}

__global__ __launch_bounds__(256) void k_qo_f32(const float* __restrict__ x, const float* __restrict__ g,
                                            const float* __restrict__ wq, const float* __restrict__ wo,
                                            const float* __restrict__ ws, float* __restrict__ out){
    __shared__ float qT[512][32];
    __shared__ float sAT[16][32];
    __shared__ float sB[16][128];
    __shared__ float rl[32];
    __shared__ float KVl[256];
    __shared__ float Ksl[256];
    __shared__ float zb[256];
    const int t  = threadIdx.x;
    const int r0 = blockIdx.x * 32;
    const int b  = r0 / SEQ;
    if(t<32) rl[t] = ws[OFF_R + r0 + t];
    KVl[t] = ws[OFF_KV + b*256 + t];
    Ksl[t] = ws[OFF_KS + b*256 + t];
    const int ti = t & 7, tj = t >> 3;
    const int ri = ti*4, cj = tj*4;
    const int srow = t & 31, skk = (t>>5)*2;
    const int sj = t & 127, skkB = (t>>7)*8;
    const float* xrow = x + (size_t)(r0+srow)*DIM + skk;
    const float* gp = g + skk;
    __syncthreads();
    const float rr = rl[srow];
    for(int ct=0; ct<4; ct++){
        const float* wqb = wq + (size_t)(ct*128 + sj)*DIM + skkB;
        float acc[4][4];
        #pragma unroll
        for(int i=0;i<4;i++)
            #pragma unroll
            for(int j=0;j<4;j++) acc[i][j]=0.f;
        for(int k0=0;k0<DIM;k0+=16){
            float2 xa = *(const float2*)(xrow + k0);
            float2 ga = *(const float2*)(gp + k0);
            float4 wa = *(const float4*)(wqb + k0);
            float4 wb2= *(const float4*)(wqb + k0 + 4);
            __syncthreads();
            sAT[skk+0][srow] = xa.x*ga.x*rr;
            sAT[skk+1][srow] = xa.y*ga.y*rr;
            sB[skkB+0][sj]=wa.x; sB[skkB+1][sj]=wa.y; sB[skkB+2][sj]=wa.z; sB[skkB+3][sj]=wa.w;
            sB[skkB+4][sj]=wb2.x; sB[skkB+5][sj]=wb2.y; sB[skkB+6][sj]=wb2.z; sB[skkB+7][sj]=wb2.w;
            __syncthreads();
            #pragma unroll
            for(int kk=0;kk<16;kk++){
                float4 a = *(const float4*)&sAT[kk][ri];
                float4 bb= *(const float4*)&sB[kk][cj];
                float av[4]={a.x,a.y,a.z,a.w};
                float bv[4]={bb.x,bb.y,bb.z,bb.w};
                #pragma unroll
                for(int i=0;i<4;i++)
                    #pragma unroll
                    for(int j=0;j<4;j++)
                        acc[i][j] = fmaf(av[i], bv[j], acc[i][j]);
            }
        }
        #pragma unroll
        for(int i=0;i<4;i++)
            #pragma unroll
            for(int j=0;j<4;j++)
                qT[ct*128+cj+j][ri+i] = phi_f(acc[i][j]*SCALE);
    }
    __syncthreads();
    {
        const int row = t>>3, h = t&7;
        const float* ks = &Ksl[(h>>1)*64];
        float z = 0.f;
        #pragma unroll
        for(int d=0;d<64;d++) z = fmaf(qT[h*64+d][row], ks[d], z);
        zb[row*8+h] = 1.0f/(z + 1e-6f);
    }
    __syncthreads();
    #pragma unroll 4
    for(int i2=0;i2<64;i2++){
        int f = i2*256 + t;
        int col = f>>5, row = f&31;
        int h = col>>6;
        float kvv = KVl[((h>>1)<<6) + (col&63)];
        qT[col][row] *= kvv * zb[row*8+h];
    }
    __syncthreads();
    for(int ct=0;ct<4;ct++){
        const float* wob = wo + (size_t)(ct*128 + sj)*DIM + skkB;
        float acc[4][4];
        #pragma unroll
        for(int i=0;i<4;i++)
            #pragma unroll
            for(int j=0;j<4;j++) acc[i][j]=0.f;
        for(int k0=0;k0<DIM;k0+=16){
            float4 wa = *(const float4*)(wob + k0);
            float4 wb2= *(const float4*)(wob + k0 + 4);
            __syncthreads();
            sB[skkB+0][sj]=wa.x; sB[skkB+1][sj]=wa.y; sB[skkB+2][sj]=wa.z; sB[skkB+3][sj]=wa.w;
            sB[skkB+4][sj]=wb2.x; sB[skkB+5][sj]=wb2.y; sB[skkB+6][sj]=wb2.z; sB[skkB+7][sj]=wb2.w;
            __syncthreads();
            #pragma unroll
            for(int kk=0;kk<16;kk++){
                float4 a = *(const float4*)&qT[k0+kk][ri];
                float4 bb= *(const float4*)&sB[kk][cj];
                float av[4]={a.x,a.y,a.z,a.w};
                float bv[4]={bb.x,bb.y,bb.z,bb.w};
                #pragma unroll
                for(int i=0;i<4;i++)
                    #pragma unroll
                    for(int j=0;j<4;j++)
                        acc[i][j] = fmaf(av[i], bv[j], acc[i][j]);
            }
        }
        #pragma unroll
        for(int i=0;i<4;i++){
            float4 st; st.x=acc[i][0]; st.y=acc[i][1]; st.z=acc[i][2]; st.w=acc[i][3];
            *(float4*)(out + (size_t)(r0+ri+i)*DIM + ct*128 + cj) = st;
        }
    }
}

extern "C" void kernel_launch(void* const* d_in, const int* in_sizes, int n_in,
                              void* d_out, int out_size, void* d_ws, size_t ws_size,
                              hipStream_t stream){
    (void)in_sizes; (void)n_in; (void)out_size;
    const float* x  = (const float*)d_in[0];
    const float* g  = (const float*)d_in[1];
    const float* wq = (const float*)d_in[2];
    const float* wk = (const float*)d_in[3];
    const float* wv = (const float*)d_in[4];
    const float* wo = (const float*)d_in[5];
    float* out = (float*)d_out;

    if(ws_size >= WS_NEED){
        float* wsf = (float*)d_ws;
        ushort_t* wqb  = (ushort_t*)((char*)d_ws + 8192);
        ushort_t* wob  = wqb  + 262144;
        ushort_t* wkvb = wob  + 262144;
        ushort_t* hb   = wkvb + 262144;

        hipLaunchKernelGGL(k_rmsh,  dim3(RTOT/4),  dim3(256), 0, stream, x, g, wsf, hb);
        hipLaunchKernelGGL(k_wcast, dim3(768),     dim3(256), 0, stream, wq, wk, wv, wo, wqb, wob, wkvb);
        hipLaunchKernelGGL(k_kv2,   dim3(RTOT/64), dim3(256), 0, stream, hb, wkvb, wsf);
        hipLaunchKernelGGL(k_qout,  dim3(RTOT/64), dim3(256), 0, stream, hb, wqb, wob, wsf, out);
    } else {
        float* ws = (float*)d_ws;
        hipLaunchKernelGGL(k_rms_f32, dim3(RTOT/4),      dim3(256), 0, stream, x, ws);
        hipLaunchKernelGGL(k_kv_f32,  dim3(RTOT/128, 4), dim3(256), 0, stream, x, g, wk, wv, ws);
        hipLaunchKernelGGL(k_qo_f32,  dim3(RTOT/32),     dim3(256), 0, stream, x, g, wq, wo, ws, out);
    }
}